// Round 1
// baseline (280.564 us; speedup 1.0000x reference)
//
#include <hip/hip_runtime.h>
#include <hip/hip_bf16.h>
#include <cstdint>

// SelfAttention: B=4, S=4096, D=256, DK=256, causal, fp32 I/O, bf16 MFMA internals.
// ws layout (assumes ws_size >= ~26 MB):
//   [0)        Wt: 3 x 256 x 256 bf16 (W transposed; Wq scaled by log2(e)/16)
//   [512K)     Q:  16384 x 256 bf16 row-major (scale folded in)
//   [+8M)      K:  16384 x 256 bf16 row-major
//   [+8M)      Vt: [4][256][4096] bf16, V transposed, s-permuted within 64-blocks
//              (s' = 32a+8g+4h+r for s_local = 32a+16h+4g+r) so PV B-fragments
//              are contiguous 16B ds_read_b128 matching the P (C/D) fragment layout.

typedef __bf16 b8v __attribute__((ext_vector_type(8)));
typedef __bf16 b4v __attribute__((ext_vector_type(4)));
typedef float  f4v __attribute__((ext_vector_type(4)));
typedef int    i4v __attribute__((ext_vector_type(4)));

#define MFMA16(a, b, c) __builtin_amdgcn_mfma_f32_16x16x32_bf16((a), (b), (c), 0, 0, 0)

#define SCALE_Q 0.09016844005f  // log2(e) / sqrt(256)

static constexpr size_t WS_WT = 0;
static constexpr size_t WS_Q  = 524288;
static constexpr size_t WS_K  = WS_Q + 8388608;
static constexpr size_t WS_VT = WS_K + 8388608;

// ---------------------------------------------------------------- prep: W -> Wt bf16
__global__ void prep_wt(const float* __restrict__ Wq, const float* __restrict__ Wk,
                        const float* __restrict__ Wv, __bf16* __restrict__ wt) {
  int gid = blockIdx.x * blockDim.x + threadIdx.x;  // 0 .. 3*65536-1
  int w = gid >> 16, rem = gid & 65535;
  int c = rem >> 8, d = rem & 255;
  const float* W = (w == 0) ? Wq : (w == 1) ? Wk : Wv;
  float v = W[d * 256 + c];
  if (w == 0) v *= SCALE_Q;
  wt[gid] = (__bf16)v;  // wt[w][c][d] = W[d][c]
}

// ---------------------------------------------------------------- proj: x @ W -> Q,K,Vt
__global__ void __launch_bounds__(256, 2) proj_qkv(
    const float* __restrict__ x, const __bf16* __restrict__ wt,
    __bf16* __restrict__ Qw, __bf16* __restrict__ Kw, __bf16* __restrict__ Vt) {
  __shared__ __bf16 w_lds[64][264];  // one 64-col tile of Wt, +8 pad
  __shared__ __bf16 v_lds[64][72];   // V transpose staging per col-tile
  const int tid = threadIdx.x;
  const int wv = tid >> 6, lane = tid & 63, c = lane & 15, g = lane >> 4;
  const int bid = blockIdx.x;
  const int rowbase = bid * 64;           // flattened b*4096+s row base
  const int batch = bid >> 6, sblk = bid & 63;

  // A-fragments of x (wave's 16 rows, all K=256), converted to bf16, kept in regs
  b8v xf[8];
  {
    const float* xr = x + (size_t)(rowbase + wv * 16 + c) * 256;
#pragma unroll
    for (int ks = 0; ks < 8; ++ks) {
      const float4 a0 = *reinterpret_cast<const float4*>(xr + 32 * ks + 8 * g);
      const float4 a1 = *reinterpret_cast<const float4*>(xr + 32 * ks + 8 * g + 4);
      b8v f;
      f[0] = (__bf16)a0.x; f[1] = (__bf16)a0.y; f[2] = (__bf16)a0.z; f[3] = (__bf16)a0.w;
      f[4] = (__bf16)a1.x; f[5] = (__bf16)a1.y; f[6] = (__bf16)a1.z; f[7] = (__bf16)a1.w;
      xf[ks] = f;
    }
  }
  const int srow = tid >> 2, sch = tid & 3;
  for (int ww = 0; ww < 3; ++ww) {
    for (int ct = 0; ct < 4; ++ct) {
      __syncthreads();
      {  // stage Wt tile: cols [ct*64, ct*64+64), all 256 d
        const i4v* src = reinterpret_cast<const i4v*>(
            wt + ((size_t)(ww * 256 + ct * 64 + srow)) * 256 + sch * 64);
        i4v* dst = reinterpret_cast<i4v*>(&w_lds[srow][sch * 64]);
#pragma unroll
        for (int j = 0; j < 8; ++j) dst[j] = src[j];
      }
      __syncthreads();
      f4v pacc[4];
#pragma unroll
      for (int i = 0; i < 4; ++i) pacc[i] = (f4v){0.f, 0.f, 0.f, 0.f};
#pragma unroll
      for (int ks = 0; ks < 8; ++ks) {
#pragma unroll
        for (int nf = 0; nf < 4; ++nf) {
          b8v wf = *reinterpret_cast<const b8v*>(&w_lds[16 * nf + c][32 * ks + 8 * g]);
          pacc[nf] = MFMA16(xf[ks], wf, pacc[nf]);
        }
      }
      if (ww < 2) {
        // Q / K: row-major bf16, direct (16-lane-contiguous u16 stores)
        __bf16* o = (ww == 0) ? Qw : Kw;
        const int row0 = rowbase + wv * 16 + 4 * g;
#pragma unroll
        for (int nf = 0; nf < 4; ++nf) {
          const int col = ct * 64 + 16 * nf + c;
#pragma unroll
          for (int r = 0; r < 4; ++r)
            o[(size_t)(row0 + r) * 256 + col] = (__bf16)pacc[nf][r];
        }
      } else {
        // V: transpose + permute via LDS. s_local = 16*wv + 4*g + r ->
        // s' = 32*(wv>>1) + 8*g + 4*(wv&1) + r (4 consecutive -> b64 pack)
        const int sp = 32 * (wv >> 1) + 8 * g + 4 * (wv & 1);
#pragma unroll
        for (int nf = 0; nf < 4; ++nf) {
          b4v pk;
          pk[0] = (__bf16)pacc[nf][0]; pk[1] = (__bf16)pacc[nf][1];
          pk[2] = (__bf16)pacc[nf][2]; pk[3] = (__bf16)pacc[nf][3];
          *reinterpret_cast<b4v*>(&v_lds[16 * nf + c][sp]) = pk;
        }
        __syncthreads();
        {
          const int dd = tid >> 2, ch = tid & 3;
          const b8v* sp8 = reinterpret_cast<const b8v*>(&v_lds[dd][ch * 16]);
          __bf16* dst =
              Vt + ((size_t)(batch * 256 + ct * 64 + dd)) * 4096 + sblk * 64 + ch * 16;
          reinterpret_cast<b8v*>(dst)[0] = sp8[0];
          reinterpret_cast<b8v*>(dst)[1] = sp8[1];
        }
      }
    }
  }
}

// ---------------------------------------------------------------- flash attention
// 4 waves x 16 q-rows (QBLK=64), KVBLK=64, swapped QK^T (S^T = K * Q^T) so softmax
// is lane-local per q; double-buffered LDS with register prefetch of next K/V tile.
__global__ void __launch_bounds__(256, 1) attn_fwd(
    const __bf16* __restrict__ Qw, const __bf16* __restrict__ Kw,
    const __bf16* __restrict__ Vt, float* __restrict__ out) {
  extern __shared__ char smem[];
  __bf16* K0 = reinterpret_cast<__bf16*>(smem);  // [64][264]
  __bf16* V0 = K0 + 64 * 264;                    // [256][72] (transposed, permuted)
  __bf16* K1 = V0 + 256 * 72;
  __bf16* V1 = K1 + 64 * 264;
  const int tid = threadIdx.x;
  const int wv = tid >> 6, lane = tid & 63, c = lane & 15, g = lane >> 4;
  const int bb = blockIdx.x & 3;
  const int qt = 63 - (blockIdx.x >> 2);  // heavy q-tiles dispatched first

  // Q B-fragments (wave's 16 q-rows), scale+log2e already folded in
  b8v qf[8];
  {
    const __bf16* qr = Qw + ((size_t)(bb * 4096 + qt * 64 + wv * 16 + c)) * 256;
#pragma unroll
    for (int ks = 0; ks < 8; ++ks)
      qf[ks] = *reinterpret_cast<const b8v*>(qr + 32 * ks + 8 * g);
  }
  const int krow = tid >> 2, kch = tid & 3;
  const __bf16* Kg = Kw + (size_t)bb * 4096 * 256;
  const __bf16* Vg = Vt + ((size_t)(bb * 256 + tid)) * 4096;
  {  // stage tile 0 into buf0
    const i4v* ksrc = reinterpret_cast<const i4v*>(Kg + (size_t)krow * 256 + kch * 64);
    i4v* kdst = reinterpret_cast<i4v*>(K0 + krow * 264 + kch * 64);
#pragma unroll
    for (int j = 0; j < 8; ++j) kdst[j] = ksrc[j];
    const i4v* vsrc = reinterpret_cast<const i4v*>(Vg);
    i4v* vdst = reinterpret_cast<i4v*>(V0 + tid * 72);
#pragma unroll
    for (int j = 0; j < 8; ++j) vdst[j] = vsrc[j];
  }
  __syncthreads();

  f4v acc[16];
#pragma unroll
  for (int i = 0; i < 16; ++i) acc[i] = (f4v){0.f, 0.f, 0.f, 0.f};
  float m = -INFINITY, lsum = 0.f;

  for (int t = 0; t <= qt; ++t) {
    const __bf16* Kc = (t & 1) ? K1 : K0;
    const __bf16* Vc = (t & 1) ? V1 : V0;
    __bf16* Kn = (t & 1) ? K0 : K1;
    __bf16* Vn = (t & 1) ? V0 : V1;
    i4v kr[8], vr[8];
    const bool pref = (t < qt);
    if (pref) {  // issue next tile's global loads early; write to LDS post-compute
      const i4v* ksrc = reinterpret_cast<const i4v*>(
          Kg + (size_t)((t + 1) * 64 + krow) * 256 + kch * 64);
#pragma unroll
      for (int j = 0; j < 8; ++j) kr[j] = ksrc[j];
      const i4v* vsrc = reinterpret_cast<const i4v*>(Vg + (t + 1) * 64);
#pragma unroll
      for (int j = 0; j < 8; ++j) vr[j] = vsrc[j];
    }
    // S^T = K * Q^T : lane holds S^T[16mf+4g+r][q=c]
    f4v sc[4];
#pragma unroll
    for (int mf = 0; mf < 4; ++mf) {
      f4v s = (f4v){0.f, 0.f, 0.f, 0.f};
#pragma unroll
      for (int ks = 0; ks < 8; ++ks) {
        b8v kf = *reinterpret_cast<const b8v*>(Kc + (c + 16 * mf) * 264 + 32 * ks + 8 * g);
        s = MFMA16(kf, qf[ks], s);
      }
      sc[mf] = s;
    }
    if (t == qt) {  // causal mask, diagonal tile only
      const int qloc = wv * 16 + c;
#pragma unroll
      for (int mf = 0; mf < 4; ++mf)
#pragma unroll
        for (int r = 0; r < 4; ++r)
          if (16 * mf + 4 * g + r > qloc) sc[mf][r] = -INFINITY;
    }
    // online softmax (base-2; scale folded into Q)
    float pmax = -INFINITY;
#pragma unroll
    for (int mf = 0; mf < 4; ++mf)
#pragma unroll
      for (int r = 0; r < 4; ++r) pmax = fmaxf(pmax, sc[mf][r]);
    pmax = fmaxf(pmax, __shfl_xor(pmax, 16));
    pmax = fmaxf(pmax, __shfl_xor(pmax, 32));
    const float mnew = fmaxf(m, pmax);
    const float fac = exp2f(m - mnew);
    float p[4][4];
    float ts = 0.f;
#pragma unroll
    for (int mf = 0; mf < 4; ++mf)
#pragma unroll
      for (int r = 0; r < 4; ++r) {
        const float e = exp2f(sc[mf][r] - mnew);
        p[mf][r] = e;
        ts += e;
      }
    ts += __shfl_xor(ts, 16);
    ts += __shfl_xor(ts, 32);
    lsum = lsum * fac + ts;
    m = mnew;
    // rescale O: acc reg r is q-row 4g+r; factor lives at lane (l&15)==q-row
    f4v fv;
#pragma unroll
    for (int r = 0; r < 4; ++r) fv[r] = __shfl(fac, 4 * g + r);
#pragma unroll
    for (int i = 0; i < 16; ++i) acc[i] *= fv;
    // P fragments: slot b of kstep ks holds P[q=c][k=32ks+16(b>>2)+4g+(b&3)]
    b8v pa0, pa1;
#pragma unroll
    for (int r = 0; r < 4; ++r) {
      pa0[r] = (__bf16)p[0][r];
      pa0[4 + r] = (__bf16)p[1][r];
      pa1[r] = (__bf16)p[2][r];
      pa1[4 + r] = (__bf16)p[3][r];
    }
    // O += P * V  (V tile pre-permuted so B-frag = one b128 per (nf, ks))
#pragma unroll
    for (int nf = 0; nf < 16; ++nf) {
      const __bf16* vrow = Vc + (16 * nf + c) * 72;
      const b8v v0 = *reinterpret_cast<const b8v*>(vrow + 8 * g);
      const b8v v1 = *reinterpret_cast<const b8v*>(vrow + 32 + 8 * g);
      acc[nf] = MFMA16(pa0, v0, acc[nf]);
      acc[nf] = MFMA16(pa1, v1, acc[nf]);
    }
    if (pref) {  // write prefetched tile into the other buffer
      i4v* kdst = reinterpret_cast<i4v*>(Kn + krow * 264 + kch * 64);
#pragma unroll
      for (int j = 0; j < 8; ++j) kdst[j] = kr[j];
      i4v* vdst = reinterpret_cast<i4v*>(Vn + tid * 72);
#pragma unroll
      for (int j = 0; j < 8; ++j) vdst[j] = vr[j];
    }
    __syncthreads();  // single barrier per tile: protects both buffers
  }
  // epilogue: normalize by 1/l (per q-row, shuffled to acc layout), fp32 out
  const float rcp = 1.f / lsum;
  f4v iv;
#pragma unroll
  for (int r = 0; r < 4; ++r) iv[r] = __shfl(rcp, 4 * g + r);
  const size_t orow = (size_t)(bb * 4096 + qt * 64 + wv * 16 + 4 * g) * 256;
#pragma unroll
  for (int nf = 0; nf < 16; ++nf) {
    const int col = 16 * nf + c;
#pragma unroll
    for (int r = 0; r < 4; ++r)
      out[orow + (size_t)r * 256 + col] = acc[nf][r] * iv[r];
  }
}

// ---------------------------------------------------------------- launch
extern "C" void kernel_launch(void* const* d_in, const int* in_sizes, int n_in,
                              void* d_out, int out_size, void* d_ws, size_t ws_size,
                              hipStream_t stream) {
  const float* x  = reinterpret_cast<const float*>(d_in[0]);
  const float* Wq = reinterpret_cast<const float*>(d_in[1]);
  const float* Wk = reinterpret_cast<const float*>(d_in[2]);
  const float* Wv = reinterpret_cast<const float*>(d_in[3]);
  char* ws = reinterpret_cast<char*>(d_ws);
  __bf16* wt = reinterpret_cast<__bf16*>(ws + WS_WT);
  __bf16* Qw = reinterpret_cast<__bf16*>(ws + WS_Q);
  __bf16* Kw = reinterpret_cast<__bf16*>(ws + WS_K);
  __bf16* Vt = reinterpret_cast<__bf16*>(ws + WS_VT);
  float* out = reinterpret_cast<float*>(d_out);

  prep_wt<<<768, 256, 0, stream>>>(Wq, Wk, Wv, wt);
  proj_qkv<<<256, 256, 0, stream>>>(x, wt, Qw, Kw, Vt);
  constexpr int kSmem = (64 * 264 + 256 * 72) * 2 * 2;  // 141,312 B
  (void)hipFuncSetAttribute(reinterpret_cast<const void*>(attn_fwd),
                            hipFuncAttributeMaxDynamicSharedMemorySize, kSmem);
  attn_fwd<<<256, 256, kSmem, stream>>>(Qw, Kw, Vt, out);
}

// Round 2
// 200.043 us; speedup vs baseline: 1.4025x; 1.4025x over previous
//
#include <hip/hip_runtime.h>
#include <hip/hip_bf16.h>
#include <cstdint>

// SelfAttention: B=4, S=4096, D=256, DK=256, causal, fp32 I/O, bf16 MFMA internals.
// Round 2: split-KV flash (chunks of C kv-tiles per block) + combine kernel for
// occupancy & causal load balance; single-buffer LDS (70.7KB -> 2 blocks/CU);
// conflict-free K staging; heavy-first + XCD-aware block mapping; setprio on MFMA.
//
// ws layout:
//   [0)        Wt: 3 x 256 x 256 bf16 (proj phase) / ml: [slot][64][2] f32 (attn phase)
//   [512K)     Q:  16384 x 256 bf16 row-major (scale log2(e)/16 folded in)
//   [+8M)      K:  16384 x 256 bf16 row-major
//   [+8M)      Vt: [4][256][4096] bf16, V transposed, s-permuted within 64-blocks
//   [+8M)      part: [slot][64][256] bf16 unnormalized partial O (split-KV only)

typedef __bf16 b8v __attribute__((ext_vector_type(8)));
typedef __bf16 b4v __attribute__((ext_vector_type(4)));
typedef float  f4v __attribute__((ext_vector_type(4)));
typedef int    i4v __attribute__((ext_vector_type(4)));

#define MFMA16(a, b, c) __builtin_amdgcn_mfma_f32_16x16x32_bf16((a), (b), (c), 0, 0, 0)

#define SCALE_Q 0.09016844005f  // log2(e) / sqrt(256)

static constexpr size_t WS_WT = 0;            // 384KB, dead after proj
static constexpr size_t WS_ML = 0;            // ml reuses Wt region (attn phase)
static constexpr size_t WS_Q  = 524288;
static constexpr size_t WS_K  = WS_Q + 8388608;
static constexpr size_t WS_VT = WS_K + 8388608;
static constexpr size_t WS_PART = WS_VT + 8388608;  // 25,952,256

// ---------------------------------------------------------------- prep: W -> Wt bf16
__global__ void prep_wt(const float* __restrict__ Wq, const float* __restrict__ Wk,
                        const float* __restrict__ Wv, __bf16* __restrict__ wt) {
  int gid = blockIdx.x * blockDim.x + threadIdx.x;  // 0 .. 3*65536-1
  int w = gid >> 16, rem = gid & 65535;
  int c = rem >> 8, d = rem & 255;
  const float* W = (w == 0) ? Wq : (w == 1) ? Wk : Wv;
  float v = W[d * 256 + c];
  if (w == 0) v *= SCALE_Q;
  wt[gid] = (__bf16)v;  // wt[w][c][d] = W[d][c]
}

// ---------------------------------------------------------------- proj: x @ W -> Q,K,Vt
__global__ void __launch_bounds__(256, 2) proj_qkv(
    const float* __restrict__ x, const __bf16* __restrict__ wt,
    __bf16* __restrict__ Qw, __bf16* __restrict__ Kw, __bf16* __restrict__ Vt) {
  __shared__ __bf16 w_lds[64][264];
  __shared__ __bf16 v_lds[64][72];
  const int tid = threadIdx.x;
  const int wv = tid >> 6, lane = tid & 63, c = lane & 15, g = lane >> 4;
  const int bid = blockIdx.x;
  const int rowbase = bid * 64;
  const int batch = bid >> 6, sblk = bid & 63;

  b8v xf[8];
  {
    const float* xr = x + (size_t)(rowbase + wv * 16 + c) * 256;
#pragma unroll
    for (int ks = 0; ks < 8; ++ks) {
      const float4 a0 = *reinterpret_cast<const float4*>(xr + 32 * ks + 8 * g);
      const float4 a1 = *reinterpret_cast<const float4*>(xr + 32 * ks + 8 * g + 4);
      b8v f;
      f[0] = (__bf16)a0.x; f[1] = (__bf16)a0.y; f[2] = (__bf16)a0.z; f[3] = (__bf16)a0.w;
      f[4] = (__bf16)a1.x; f[5] = (__bf16)a1.y; f[6] = (__bf16)a1.z; f[7] = (__bf16)a1.w;
      xf[ks] = f;
    }
  }
  const int srow = tid >> 2, sch = tid & 3;
  for (int ww = 0; ww < 3; ++ww) {
    for (int ct = 0; ct < 4; ++ct) {
      __syncthreads();
      {
        const i4v* src = reinterpret_cast<const i4v*>(
            wt + ((size_t)(ww * 256 + ct * 64 + srow)) * 256 + sch * 64);
        i4v* dst = reinterpret_cast<i4v*>(&w_lds[srow][sch * 64]);
#pragma unroll
        for (int j = 0; j < 8; ++j) dst[j] = src[j];
      }
      __syncthreads();
      f4v pacc[4];
#pragma unroll
      for (int i = 0; i < 4; ++i) pacc[i] = (f4v){0.f, 0.f, 0.f, 0.f};
#pragma unroll
      for (int ks = 0; ks < 8; ++ks) {
#pragma unroll
        for (int nf = 0; nf < 4; ++nf) {
          b8v wf = *reinterpret_cast<const b8v*>(&w_lds[16 * nf + c][32 * ks + 8 * g]);
          pacc[nf] = MFMA16(xf[ks], wf, pacc[nf]);
        }
      }
      if (ww < 2) {
        __bf16* o = (ww == 0) ? Qw : Kw;
        const int row0 = rowbase + wv * 16 + 4 * g;
#pragma unroll
        for (int nf = 0; nf < 4; ++nf) {
          const int col = ct * 64 + 16 * nf + c;
#pragma unroll
          for (int r = 0; r < 4; ++r)
            o[(size_t)(row0 + r) * 256 + col] = (__bf16)pacc[nf][r];
        }
      } else {
        const int sp = 32 * (wv >> 1) + 8 * g + 4 * (wv & 1);
#pragma unroll
        for (int nf = 0; nf < 4; ++nf) {
          b4v pk;
          pk[0] = (__bf16)pacc[nf][0]; pk[1] = (__bf16)pacc[nf][1];
          pk[2] = (__bf16)pacc[nf][2]; pk[3] = (__bf16)pacc[nf][3];
          *reinterpret_cast<b4v*>(&v_lds[16 * nf + c][sp]) = pk;
        }
        __syncthreads();
        {
          const int dd = tid >> 2, ch = tid & 3;
          const b8v* sp8 = reinterpret_cast<const b8v*>(&v_lds[dd][ch * 16]);
          __bf16* dst =
              Vt + ((size_t)(batch * 256 + ct * 64 + dd)) * 4096 + sblk * 64 + ch * 16;
          reinterpret_cast<b8v*>(dst)[0] = sp8[0];
          reinterpret_cast<b8v*>(dst)[1] = sp8[1];
        }
      }
    }
  }
}

// ---------------------------------------------------------------- flash attention (split-KV)
// Block = 4 waves, QBLK=64 (16 q-rows/wave via swapped QK^T), KVBLK=64.
// Block (b, qt, ch) processes kv-tiles [ch*C, min(qt, (ch+1)*C-1)]; if the q-tile
// has one chunk, writes normalized fp32 out directly; else writes bf16 partial
// acc + (m,l) for the combine kernel. Single-buffer LDS, reg-prefetch, 2 barriers.
__global__ void __launch_bounds__(256, 2) attn_fwd(
    const __bf16* __restrict__ Qw, const __bf16* __restrict__ Kw,
    const __bf16* __restrict__ Vt, float* __restrict__ out,
    __bf16* __restrict__ part, float* __restrict__ ml, int sC, int SPB) {
  extern __shared__ char smem[];
  __bf16* Klds = reinterpret_cast<__bf16*>(smem);  // [64][264]
  __bf16* Vlds = Klds + 64 * 264;                  // [256][72]
  const int tid = threadIdx.x;
  const int wv = tid >> 6, lane = tid & 63, c = lane & 15, g = lane >> 4;
  const int NCH = 64 >> sC;
  // XCD-aware: batch pinned to an XCD pair; heavy q-tiles (desc) first; chunk inner.
  const int bid = blockIdx.x;
  const int bb = (bid >> 1) & 3;
  const int sub = ((bid >> 3) << 1) | (bid & 1);
  const int ch = sub & (NCH - 1);
  const int qt = 63 - (sub >> (6 - sC));
  const int t0 = ch << sC;
  if (t0 > qt) return;  // empty chunk
  const int tlast = (((ch + 1) << sC) - 1);
  const int t1 = qt < tlast ? qt : tlast;

  // Q B-fragments (wave's 16 q-rows), scale+log2e folded in
  b8v qf[8];
  {
    const __bf16* qr = Qw + ((size_t)(bb * 4096 + qt * 64 + wv * 16 + c)) * 256;
#pragma unroll
    for (int ks = 0; ks < 8; ++ks)
      qf[ks] = *reinterpret_cast<const b8v*>(qr + 32 * ks + 8 * g);
  }
  // staging map: conflict-free (bank quad = row%8 varies within 8/16-lane groups)
  const int krow = tid & 63, kch = tid >> 6;
  const __bf16* Kg = Kw + (size_t)bb * 4096 * 256;
  const __bf16* Vg = Vt + ((size_t)(bb * 256 + tid)) * 4096;
  {  // stage tile t0
    const i4v* ksrc =
        reinterpret_cast<const i4v*>(Kg + (size_t)(t0 * 64 + krow) * 256 + kch * 64);
    i4v* kdst = reinterpret_cast<i4v*>(Klds + krow * 264 + kch * 64);
#pragma unroll
    for (int j = 0; j < 8; ++j) kdst[j] = ksrc[j];
    const i4v* vsrc = reinterpret_cast<const i4v*>(Vg + t0 * 64);
    i4v* vdst = reinterpret_cast<i4v*>(Vlds + tid * 72);
#pragma unroll
    for (int j = 0; j < 8; ++j) vdst[j] = vsrc[j];
  }
  __syncthreads();

  f4v acc[16];
#pragma unroll
  for (int i = 0; i < 16; ++i) acc[i] = (f4v){0.f, 0.f, 0.f, 0.f};
  float m = -INFINITY, lsum = 0.f;

  for (int t = t0; t <= t1; ++t) {
    i4v kr[8], vr[8];
    const bool pref = (t < t1);
    if (pref) {  // issue next tile's global loads early; LDS write after barrier
      const i4v* ksrc = reinterpret_cast<const i4v*>(
          Kg + (size_t)((t + 1) * 64 + krow) * 256 + kch * 64);
#pragma unroll
      for (int j = 0; j < 8; ++j) kr[j] = ksrc[j];
      const i4v* vsrc = reinterpret_cast<const i4v*>(Vg + (t + 1) * 64);
#pragma unroll
      for (int j = 0; j < 8; ++j) vr[j] = vsrc[j];
    }
    // S^T = K * Q^T : lane holds S^T[16mf+4g+r][q=c]
    f4v sc[4];
    __builtin_amdgcn_s_setprio(1);
#pragma unroll
    for (int mf = 0; mf < 4; ++mf) {
      f4v s = (f4v){0.f, 0.f, 0.f, 0.f};
#pragma unroll
      for (int ks = 0; ks < 8; ++ks) {
        b8v kf =
            *reinterpret_cast<const b8v*>(Klds + (c + 16 * mf) * 264 + 32 * ks + 8 * g);
        s = MFMA16(kf, qf[ks], s);
      }
      sc[mf] = s;
    }
    __builtin_amdgcn_s_setprio(0);
    if (t == qt) {  // causal mask, diagonal tile only
      const int qloc = wv * 16 + c;
#pragma unroll
      for (int mf = 0; mf < 4; ++mf)
#pragma unroll
        for (int r = 0; r < 4; ++r)
          if (16 * mf + 4 * g + r > qloc) sc[mf][r] = -INFINITY;
    }
    // online softmax (base-2; scale folded into Q)
    float pmax = -INFINITY;
#pragma unroll
    for (int mf = 0; mf < 4; ++mf)
#pragma unroll
      for (int r = 0; r < 4; ++r) pmax = fmaxf(pmax, sc[mf][r]);
    pmax = fmaxf(pmax, __shfl_xor(pmax, 16));
    pmax = fmaxf(pmax, __shfl_xor(pmax, 32));
    const float mnew = fmaxf(m, pmax);
    const float fac = exp2f(m - mnew);
    float p[4][4];
    float ts = 0.f;
#pragma unroll
    for (int mf = 0; mf < 4; ++mf)
#pragma unroll
      for (int r = 0; r < 4; ++r) {
        const float e = exp2f(sc[mf][r] - mnew);
        p[mf][r] = e;
        ts += e;
      }
    ts += __shfl_xor(ts, 16);
    ts += __shfl_xor(ts, 32);
    lsum = lsum * fac + ts;
    m = mnew;
    f4v fv;
#pragma unroll
    for (int r = 0; r < 4; ++r) fv[r] = __shfl(fac, 4 * g + r);
#pragma unroll
    for (int i = 0; i < 16; ++i) acc[i] *= fv;
    b8v pa0, pa1;
#pragma unroll
    for (int r = 0; r < 4; ++r) {
      pa0[r] = (__bf16)p[0][r];
      pa0[4 + r] = (__bf16)p[1][r];
      pa1[r] = (__bf16)p[2][r];
      pa1[4 + r] = (__bf16)p[3][r];
    }
    __builtin_amdgcn_s_setprio(1);
#pragma unroll
    for (int nf = 0; nf < 16; ++nf) {
      const __bf16* vrow = Vlds + (16 * nf + c) * 72;
      const b8v v0 = *reinterpret_cast<const b8v*>(vrow + 8 * g);
      const b8v v1 = *reinterpret_cast<const b8v*>(vrow + 32 + 8 * g);
      acc[nf] = MFMA16(pa0, v0, acc[nf]);
      acc[nf] = MFMA16(pa1, v1, acc[nf]);
    }
    __builtin_amdgcn_s_setprio(0);
    __syncthreads();  // all waves done reading LDS
    if (pref) {
      i4v* kdst = reinterpret_cast<i4v*>(Klds + krow * 264 + kch * 64);
#pragma unroll
      for (int j = 0; j < 8; ++j) kdst[j] = kr[j];
      i4v* vdst = reinterpret_cast<i4v*>(Vlds + tid * 72);
#pragma unroll
      for (int j = 0; j < 8; ++j) vdst[j] = vr[j];
    }
    __syncthreads();  // writes visible
  }

  const int nch = (qt >> sC) + 1;
  if (nch == 1) {  // single chunk: normalized fp32 output directly
    const float rcp = 1.f / lsum;
    f4v iv;
#pragma unroll
    for (int r = 0; r < 4; ++r) iv[r] = __shfl(rcp, 4 * g + r);
    const size_t orow = (size_t)(bb * 4096 + qt * 64 + wv * 16 + 4 * g) * 256;
#pragma unroll
    for (int nf = 0; nf < 16; ++nf) {
      const int col = 16 * nf + c;
#pragma unroll
      for (int r = 0; r < 4; ++r)
        out[orow + (size_t)r * 256 + col] = acc[nf][r] * iv[r];
    }
  } else {  // partial: bf16 acc (unnormalized) + (m,l)
    const int gq = qt >> sC;
    const int pq = (gq + 1) * (qt - ((gq << sC) >> 1));  // prefix slots within batch
    const int slot = bb * SPB + pq + ch;
    __bf16* pdst = part + ((size_t)slot * 64 + wv * 16) * 256;
#pragma unroll
    for (int nf = 0; nf < 16; ++nf) {
      const int col = 16 * nf + c;
#pragma unroll
      for (int r = 0; r < 4; ++r)
        pdst[(size_t)(4 * g + r) * 256 + col] = (__bf16)acc[nf][r];
    }
    if (lane < 16) {
      float* mdst = ml + ((size_t)slot * 64 + wv * 16 + lane) * 2;
      mdst[0] = m;
      mdst[1] = lsum;
    }
  }
}

// ---------------------------------------------------------------- combine partials
__global__ void __launch_bounds__(256) combine_k(
    const __bf16* __restrict__ part, const float* __restrict__ ml,
    float* __restrict__ out, int sC, int SPB) {
  const int bid = blockIdx.x;
  const int bb = bid & 3;
  const int qt = (1 << sC) + (bid >> 2);
  const int nch = (qt >> sC) + 1;
  const int gq = qt >> sC;
  const int sb = bb * SPB + (gq + 1) * (qt - ((gq << sC) >> 1));
  const int row = threadIdx.x & 63, seg = threadIdx.x >> 6;

  float mv[4], lv[4];
  float mx = -INFINITY;
#pragma unroll
  for (int cc = 0; cc < 4; ++cc) {
    if (cc < nch) {
      const float* p = ml + ((size_t)(sb + cc) * 64 + row) * 2;
      mv[cc] = p[0];
      lv[cc] = p[1];
      mx = fmaxf(mx, mv[cc]);
    } else {
      mv[cc] = -INFINITY;
      lv[cc] = 0.f;
    }
  }
  float den = 0.f, wgt[4];
#pragma unroll
  for (int cc = 0; cc < 4; ++cc) {
    const float w = exp2f(mv[cc] - mx);
    wgt[cc] = w;
    den += w * lv[cc];
  }
  const float inv = 1.f / den;
  f4v o4[16];
#pragma unroll
  for (int i = 0; i < 16; ++i) o4[i] = (f4v){0.f, 0.f, 0.f, 0.f};
#pragma unroll
  for (int cc = 0; cc < 4; ++cc) {
    if (cc >= nch) continue;
    const float w = wgt[cc] * inv;
    const b8v* src = reinterpret_cast<const b8v*>(
        part + ((size_t)(sb + cc) * 64 + row) * 256 + seg * 64);
#pragma unroll
    for (int k = 0; k < 8; ++k) {
      const b8v v = src[k];
#pragma unroll
      for (int j = 0; j < 4; ++j) {
        o4[2 * k][j] += w * (float)v[j];
        o4[2 * k + 1][j] += w * (float)v[4 + j];
      }
    }
  }
  float* dst = out + ((size_t)(bb * 4096 + qt * 64 + row)) * 256 + seg * 64;
#pragma unroll
  for (int k = 0; k < 16; ++k)
    reinterpret_cast<f4v*>(dst)[k] = o4[k];
}

// ---------------------------------------------------------------- launch
extern "C" void kernel_launch(void* const* d_in, const int* in_sizes, int n_in,
                              void* d_out, int out_size, void* d_ws, size_t ws_size,
                              hipStream_t stream) {
  const float* x  = reinterpret_cast<const float*>(d_in[0]);
  const float* Wq = reinterpret_cast<const float*>(d_in[1]);
  const float* Wk = reinterpret_cast<const float*>(d_in[2]);
  const float* Wv = reinterpret_cast<const float*>(d_in[3]);
  char* ws = reinterpret_cast<char*>(d_ws);
  __bf16* wt = reinterpret_cast<__bf16*>(ws + WS_WT);
  __bf16* Qw = reinterpret_cast<__bf16*>(ws + WS_Q);
  __bf16* Kw = reinterpret_cast<__bf16*>(ws + WS_K);
  __bf16* Vt = reinterpret_cast<__bf16*>(ws + WS_VT);
  __bf16* part = reinterpret_cast<__bf16*>(ws + WS_PART);
  float* mlp = reinterpret_cast<float*>(ws + WS_ML);
  float* out = reinterpret_cast<float*>(d_out);

  // pick chunk size from available scratch: s=4 (C=16 tiles) -> 46.9MB,
  // s=5 (C=32) -> 38.5MB, else s=6 (no split, direct writes).
  int sC;
  if (ws_size >= WS_PART + 4ull * 160 * 64 * 256 * 2) sC = 4;
  else if (ws_size >= WS_PART + 4ull * 96 * 64 * 256 * 2) sC = 5;
  else sC = 6;
  const int G = 64 >> sC;
  const int SPB = (G + 1) * (64 - ((G << sC) >> 1));  // slots per batch
  const int NCH = 64 >> sC;

  prep_wt<<<768, 256, 0, stream>>>(Wq, Wk, Wv, wt);
  proj_qkv<<<256, 256, 0, stream>>>(x, wt, Qw, Kw, Vt);
  constexpr int kSmem = (64 * 264 + 256 * 72) * 2;  // 70,656 B -> 2 blocks/CU
  (void)hipFuncSetAttribute(reinterpret_cast<const void*>(attn_fwd),
                            hipFuncAttributeMaxDynamicSharedMemorySize, kSmem);
  attn_fwd<<<256 * NCH, 256, kSmem, stream>>>(Qw, Kw, Vt, out, part, mlp, sC, SPB);
  if (sC < 6)
    combine_k<<<4 * (64 - (1 << sC)), 256, 0, stream>>>(part, mlp, out, sC, SPB);
}